// Round 12
// baseline (169.819 us; speedup 1.0000x reference)
//
#include <hip/hip_runtime.h>
#include <math.h>

#define H 4
#define NL 5
#define SEQ 610
#define BATCH 128
// 2-tick per-layer handoff: layer l computes timestep t = tau - 2*l.
#define NITER 619
#define HEAD 16      // gated head ticks
#define TAIL0 616    // HEAD + 75*8 ; ticks 616..618 are the gated tail

typedef float v2f __attribute__((ext_vector_type(2)));

#if __has_builtin(__builtin_elementwise_fma)
#define FMA2(a, b, c) __builtin_elementwise_fma((a), (b), (c))
#else
static __device__ __forceinline__ v2f FMA2(v2f a, v2f b, v2f c) {
    v2f r; r[0] = fmaf(a[0], b[0], c[0]); r[1] = fmaf(a[1], b[1], c[1]); return r;
}
#endif

static __device__ __forceinline__ v2f splat2(float a) { v2f r; r[0] = a; r[1] = a; return r; }

// Eigen-style 13/6-degree rational tanh (TF/XLA default), ~ulp accuracy |x|<=7.9
#define TANH_A1  4.89352455891786e-03f
#define TANH_A3  6.37261928875436e-04f
#define TANH_A5  1.48572235717979e-05f
#define TANH_A7  5.12229709037114e-08f
#define TANH_A9  (-8.60467152213735e-11f)
#define TANH_A11 2.00018790482477e-13f
#define TANH_A13 (-2.76076847742355e-16f)
#define TANH_B0  4.89352518554385e-03f
#define TANH_B2  2.26843463243900e-03f
#define TANH_B4  1.18534705686654e-04f
#define TANH_B6  1.19825839466702e-06f
#define TANH_CLAMP 7.90531110763549805f

// update_dpp on float. CTRL: quad_perm 0x00/0x55/0xAA/0xFF, row_shr:4 0x114,
// row_bcast15 0x142. BC: true -> 0 on invalid src, false -> keep `old`.
template<int CTRL, bool BC>
__device__ __forceinline__ float dpp1(float old_, float src) {
    return __int_as_float(__builtin_amdgcn_update_dpp(
        __float_as_int(old_), __float_as_int(src), CTRL, 0xF, 0xF, BC));
}

// Lane layout (per 32-lane half = one batch row):
//   r = lane&31; layers 0-3 = quads 0-3 (r=0..15), layer 4 = lanes 16-19;
//   r>=20 computes junk (never written out).
// Gate math packed as pairs {gate0,gate1}/{gate2,gate3} -> v_pk_fma_f32.
// h = o*tanh(c) via rational tanh with Ao folded into the single division:
//   h = (c*P(c^2)) * rcp(Q(c^2)*Ao)   -- removes exp2+rcp from the c->h chain.
__global__ __launch_bounds__(64) void lstm_rt_kernel(
    const float* __restrict__ x,      // [128,610,2]
    const float* __restrict__ w_ih0,  // [16,2]
    const float* __restrict__ w_ih,   // [4,16,4]
    const float* __restrict__ w_hh,   // [5,16,4]
    const float* __restrict__ b_ih,   // [5,16]
    const float* __restrict__ b_hh,   // [5,16]
    const float* __restrict__ w_lin,  // [1,4]
    const float* __restrict__ b_lin,  // [1]
    const float* __restrict__ w_fc,   // [5,610]
    const float* __restrict__ b_fc,   // [5]
    float* __restrict__ out)          // [128,5]
{
    __shared__ float lds_x[2 * SEQ * 2 + 32];   // [2][610][2] + pad (tail over-reads)
    __shared__ float lds_wfcp[4 * SEQ * 2 + 8]; // [4][610][2] = {wfc[k][t], wfc[4][t]}

    const int lane = threadIdx.x;
    const int half = lane >> 5;
    const int r    = lane & 31;
    const int l    = r >> 2;
    const int k    = r & 3;
    const int lw   = l > 4 ? 4 : l;
    const bool is_l0 = (l == 0);
    const int row  = blockIdx.x * 2 + half;

    // ---- stage x rows + paired w_fc into LDS, coalesced ----
    #pragma unroll
    for (int hh = 0; hh < 2; ++hh) {
        const float4* src = (const float4*)(x + (size_t)(blockIdx.x * 2 + hh) * (SEQ * 2));
        float4* dst = (float4*)&lds_x[hh * (SEQ * 2)];
        for (int i = lane; i < (SEQ * 2) / 4; i += 64) dst[i] = src[i];
    }
    #pragma unroll
    for (int kk = 0; kk < 4; ++kk) {
        for (int t = lane; t < SEQ; t += 64) {
            lds_wfcp[(kk * SEQ + t) * 2 + 0] = w_fc[kk * SEQ + t];
            lds_wfcp[(kk * SEQ + t) * 2 + 1] = w_fc[4 * SEQ + t];
        }
    }
    __syncthreads();

    // ---- per-lane weights, pre-scaled by log2e, packed as gate pairs ----
    // pair01 = {gate i, gate f}; pair23 = {gate g, gate o}
    v2f wip01[4], wip23[4], whp01[4], whp23[4], b01, b23;
    {
        float wi[4][4], wh[4][4], bias[4];
        #pragma unroll
        for (int j = 0; j < 4; ++j) {
            const float s = (j == 2) ? 2.8853900817779268f   // +2*log2(e) for g
                                     : -1.4426950408889634f; // -log2(e) for i,f,o
            const int wrow = j * H + k;
            if (lw == 0) {
                wi[j][0] = w_ih0[wrow * 2 + 0] * s;
                wi[j][1] = w_ih0[wrow * 2 + 1] * s;
                wi[j][2] = 0.f; wi[j][3] = 0.f;
            } else {
                const float4 v = *(const float4*)&w_ih[((lw - 1) * 16 + wrow) * 4];
                wi[j][0] = v.x * s; wi[j][1] = v.y * s; wi[j][2] = v.z * s; wi[j][3] = v.w * s;
            }
            const float4 u = *(const float4*)&w_hh[(lw * 16 + wrow) * 4];
            wh[j][0] = u.x * s; wh[j][1] = u.y * s; wh[j][2] = u.z * s; wh[j][3] = u.w * s;
            bias[j] = (b_ih[lw * 16 + wrow] + b_hh[lw * 16 + wrow]) * s;
        }
        #pragma unroll
        for (int m = 0; m < 4; ++m) {
            wip01[m][0] = wi[0][m]; wip01[m][1] = wi[1][m];
            wip23[m][0] = wi[2][m]; wip23[m][1] = wi[3][m];
            whp01[m][0] = wh[0][m]; whp01[m][1] = wh[1][m];
            whp23[m][0] = wh[2][m]; whp23[m][1] = wh[3][m];
        }
        b01[0] = bias[0]; b01[1] = bias[1];
        b23[0] = bias[2]; b23[1] = bias[3];
    }
    const float wl0 = w_lin[0], wl1 = w_lin[1], wl2 = w_lin[2], wl3 = w_lin[3];
    const float bl  = b_lin[0];

    const int xb     = half * (SEQ * 2);
    const int wpbase = k * SEQ;

    // ---- state ----
    float c = 0.f;
    float q0 = 0.f, q1 = 0.f, q2 = 0.f, q3 = 0.f;   // h(tau-1) of own layer, gathered
    float accA = 0.f, accB = 0.f;
    v2f pre01, pre23;                                // gate pre-activations for chain(tau)
    {
        const float2 xv0 = *(const float2*)&lds_x[xb];
        const float xs0 = is_l0 ? xv0.x : 0.f;
        const float xs1 = is_l0 ? xv0.y : 0.f;
        pre01 = FMA2(wip01[1], splat2(xs1), FMA2(wip01[0], splat2(xs0), b01));
        pre23 = FMA2(wip23[1], splat2(xs1), FMA2(wip23[0], splat2(xs0), b23));
    }

    #define TICK_CORE(tau_, GATED, NXv, WVv)                                          \
    {                                                                                 \
        const float oq0 = q0, oq1 = q1, oq2 = q2, oq3 = q3;                           \
        /* ---- CHAIN: packed gates -> c -> h (rational tanh) -> quad DPP ---- */     \
        v2f G01 = FMA2(whp01[3], splat2(oq3), FMA2(whp01[2], splat2(oq2),             \
                  FMA2(whp01[1], splat2(oq1), FMA2(whp01[0], splat2(oq0), pre01)))); \
        v2f G23 = FMA2(whp23[3], splat2(oq3), FMA2(whp23[2], splat2(oq2),             \
                  FMA2(whp23[1], splat2(oq1), FMA2(whp23[0], splat2(oq0), pre23)))); \
        const float Ai = 1.f + __builtin_amdgcn_exp2f(G01[0]);                        \
        const float Af = 1.f + __builtin_amdgcn_exp2f(G01[1]);                        \
        const float Dg = 1.f + __builtin_amdgcn_exp2f(G23[0]);                        \
        const float Ao = 1.f + __builtin_amdgcn_exp2f(G23[1]);                        \
        const float M   = Ai * Dg;                                                    \
        const float den = M * Af;                                                     \
        const float num = fmaf(c, M, Af * (Dg - 2.f));                                \
        float cn = num * __builtin_amdgcn_rcpf(den);                                  \
        if (GATED) { const unsigned tt = (unsigned)((tau_) - 2 * l);                  \
                     cn = (tt < SEQ) ? cn : 0.f; }                                    \
        c = cn;                                                                       \
        /* h = o*tanh(c):  (xc*P(u)) * rcp(Q(u)*Ao),  u = xc^2 (FMA-only polys) */    \
        const float xc = fminf(fmaxf(c, -TANH_CLAMP), TANH_CLAMP);                    \
        const float uu = xc * xc;                                                     \
        const float u2 = uu * uu;                                                     \
        const float u4 = u2 * u2;                                                     \
        const float pc0 = fmaf(TANH_A3, uu, TANH_A1);                                 \
        const float pc1 = fmaf(TANH_A7, uu, TANH_A5);                                 \
        const float pc2 = fmaf(TANH_A11, uu, TANH_A9);                                \
        const float pe  = fmaf(TANH_A13, u2, pc2);                                    \
        const float P   = fmaf(u4, pe, fmaf(u2, pc1, pc0));                           \
        const float Qq  = fmaf(fmaf(TANH_B6, uu, TANH_B4), u2,                        \
                               fmaf(TANH_B2, uu, TANH_B0));                           \
        const float hv  = (xc * P) * __builtin_amdgcn_rcpf(Qq * Ao);                  \
        q0 = dpp1<0x00, true>(0.f, hv);                                               \
        q1 = dpp1<0x55, true>(0.f, hv);                                               \
        q2 = dpp1<0xAA, true>(0.f, hv);                                               \
        q3 = dpp1<0xFF, true>(0.f, hv);                                               \
        /* ---- BURST (depends only on oq / chunk regs) ---- */                       \
        float p0 = dpp1<0x142, true>(0.f, oq0); p0 = dpp1<0x114, false>(p0, oq0);     \
        float p1 = dpp1<0x142, true>(0.f, oq1); p1 = dpp1<0x114, false>(p1, oq1);     \
        float p2 = dpp1<0x142, true>(0.f, oq2); p2 = dpp1<0x114, false>(p2, oq2);     \
        float p3 = dpp1<0x142, true>(0.f, oq3); p3 = dpp1<0x114, false>(p3, oq3);     \
        const float xs0 = is_l0 ? (NXv).x : p0;                                       \
        const float xs1 = is_l0 ? (NXv).y : p1;                                       \
        pre01 = FMA2(wip01[3], splat2(p3), FMA2(wip01[2], splat2(p2),                 \
                FMA2(wip01[1], splat2(xs1), FMA2(wip01[0], splat2(xs0), b01))));      \
        pre23 = FMA2(wip23[3], splat2(p3), FMA2(wip23[2], splat2(p2),                 \
                FMA2(wip23[1], splat2(xs1), FMA2(wip23[0], splat2(xs0), b23))));      \
        float tval = fmaf(oq0, wl0, fmaf(oq1, wl1, fmaf(oq2, wl2, fmaf(oq3, wl3, bl)))); \
        if (GATED) tval = ((unsigned)((tau_) - 9) < SEQ) ? tval : 0.f;                \
        accA = fmaf(tval, (WVv).x, accA);                                             \
        accB = fmaf(tval, (WVv).y, accB);                                             \
    }

    // ---- gated head: per-tick LDS loads, clamped indices ----
    for (int tau = 0; tau < HEAD; ++tau) {
        const float2 nx = *(const float2*)&lds_x[xb + (tau + 1) * 2];
        int t4 = tau - 9; t4 = t4 < 0 ? 0 : t4;
        const float2 wv = *(const float2*)&lds_wfcp[(wpbase + t4) * 2];
        TICK_CORE(tau, true, nx, wv);
    }

    // ---- clean body: 75 chunks x 8 ticks; loads batched per chunk into regs.
    // Junk timesteps (t>609) on layers 0-3 cannot reach layer-4's consumed h
    // before the loop ends; wfc index tau-9 stays in [7,606]; x over-reads stay
    // inside the padded lds_x.
    for (int ch = 0; ch < 75; ++ch) {
        const int tau0 = HEAD + ch * 8;
        float2 xc_[8], wc_[8];
        #pragma unroll
        for (int i = 0; i < 8; ++i) {
            xc_[i] = *(const float2*)&lds_x[xb + (tau0 + 1 + i) * 2];
            wc_[i] = *(const float2*)&lds_wfcp[(wpbase + tau0 + i - 9) * 2];
        }
        #pragma unroll
        for (int i = 0; i < 8; ++i) {
            TICK_CORE(tau0 + i, false, xc_[i], wc_[i]);
        }
    }

    // ---- gated tail (ticks 616..618): gating benign here ----
    for (int tau = TAIL0; tau < NITER; ++tau) {
        const float2 nx = *(const float2*)&lds_x[xb + (tau + 1) * 2];
        const float2 wv = *(const float2*)&lds_wfcp[(wpbase + tau - 9) * 2];
        TICK_CORE(tau, true, nx, wv);
    }
    #undef TICK_CORE

    if (r >= 16 && r < 20) {                // layer-4 lanes
        out[row * 5 + k] = accA + b_fc[k];
        if (k == 0) out[row * 5 + 4] = accB + b_fc[4];
    }
}

extern "C" void kernel_launch(void* const* d_in, const int* in_sizes, int n_in,
                              void* d_out, int out_size, void* d_ws, size_t ws_size,
                              hipStream_t stream)
{
    const float* x     = (const float*)d_in[0];
    const float* w_ih0 = (const float*)d_in[1];
    const float* w_ih  = (const float*)d_in[2];
    const float* w_hh  = (const float*)d_in[3];
    const float* b_ih  = (const float*)d_in[4];
    const float* b_hh  = (const float*)d_in[5];
    const float* w_lin = (const float*)d_in[6];
    const float* b_lin = (const float*)d_in[7];
    const float* w_fc  = (const float*)d_in[8];
    const float* b_fc  = (const float*)d_in[9];
    float* out = (float*)d_out;

    lstm_rt_kernel<<<dim3(BATCH / 2), dim3(64), 0, stream>>>(
        x, w_ih0, w_ih, w_hh, b_ih, b_hh, w_lin, b_lin, w_fc, b_fc, out);
}

// Round 13
// 157.005 us; speedup vs baseline: 1.0816x; 1.0816x over previous
//
#include <hip/hip_runtime.h>
#include <math.h>

#define H 4
#define NL 5
#define SEQ 610
#define BATCH 128
// 2-tick per-layer handoff: layer l computes timestep t = tau - 2*l.
#define NITER 619
#define HEAD 16      // gated head ticks
#define TAIL0 616    // HEAD + 75*8 ; ticks 616..618 are the gated tail

typedef float v2f __attribute__((ext_vector_type(2)));

#if __has_builtin(__builtin_elementwise_fma)
#define FMA2(a, b, c) __builtin_elementwise_fma((a), (b), (c))
#else
static __device__ __forceinline__ v2f FMA2(v2f a, v2f b, v2f c) {
    v2f r; r[0] = fmaf(a[0], b[0], c[0]); r[1] = fmaf(a[1], b[1], c[1]); return r;
}
#endif
static __device__ __forceinline__ v2f splat2(float a) { v2f r; r[0] = a; r[1] = a; return r; }

// update_dpp with explicit row/bank masks.
// CTRL: quad_perm 0x00/0x55/0xAA/0xFF, row_shl:4 0x104, row_shr:4 0x114,
// row_shr:8 0x118, row_bcast15 0x142 (lane15->row1, lane31->row2, lane47->row3),
// row_bcast31 0x143 (lane31->rows2,3). Masked-out lanes keep `old`;
// BC: true -> 0 on invalid src, false -> keep `old`.
template<int CTRL, int RM, int BM, bool BC>
__device__ __forceinline__ float dppm(float old_, float src) {
    return __int_as_float(__builtin_amdgcn_update_dpp(
        __float_as_int(old_), __float_as_int(src), CTRL, RM, BM, BC));
}

// Lane layout (ONE batch row per wave, 40 active lanes):
//   lane = l*8 + j2*4 + k ; layer l in lanes 8l..8l+7 (l=0..4), lanes 40-63 junk.
//   j2 selects the gate PAIR: j2=0 -> {i,f}, j2=1 -> {g,o}; k = hidden unit.
// One exp2 instruction evaluates a gate for ALL units/layers simultaneously
// (trans count/tick: 2 gate exp2 + 1 Dc exp2 + 2 rcp = 5, vs 7 in the 4-lane
// layout). Gate/pre MACs: 4 pk-FMA each (vs 8).
// Pair exchange: X={Ai,Af}, Y={Dg,Ao} built on all lanes with bank-masked
// row_shr:4 / row_shl:4 (2 DPP per element). Cross-layer handoff p_i:
// row_shr:8 (layers 1,3) + masked bcast15 (layer 2) + masked bcast31 (layer 4).
__global__ __launch_bounds__(64) void lstm_jk_kernel(
    const float* __restrict__ x,      // [128,610,2]
    const float* __restrict__ w_ih0,  // [16,2]
    const float* __restrict__ w_ih,   // [4,16,4]
    const float* __restrict__ w_hh,   // [5,16,4]
    const float* __restrict__ b_ih,   // [5,16]
    const float* __restrict__ b_hh,   // [5,16]
    const float* __restrict__ w_lin,  // [1,4]
    const float* __restrict__ b_lin,  // [1]
    const float* __restrict__ w_fc,   // [5,610]
    const float* __restrict__ b_fc,   // [5]
    float* __restrict__ out)          // [128,5]
{
    __shared__ float lds_x[SEQ * 2 + 32];       // [610][2] + pad (tail over-reads)
    __shared__ float lds_wfcp[4 * SEQ * 2 + 8]; // [4][610][2] = {wfc[k][t], wfc[4][t]}

    const int lane  = threadIdx.x;
    const int l_raw = lane >> 3;
    const int l     = l_raw > 4 ? 4 : l_raw;   // clamp for weight loads
    const int j2    = (lane >> 2) & 1;
    const int k     = lane & 3;
    const bool is_l0 = (l_raw == 0);
    const int b     = blockIdx.x;

    // ---- stage x row + paired w_fc into LDS, coalesced ----
    {
        const float4* src = (const float4*)(x + (size_t)b * (SEQ * 2));
        float4* dst = (float4*)lds_x;
        for (int i = lane; i < (SEQ * 2) / 4; i += 64) dst[i] = src[i];
    }
    #pragma unroll
    for (int kk = 0; kk < 4; ++kk) {
        for (int t = lane; t < SEQ; t += 64) {
            lds_wfcp[(kk * SEQ + t) * 2 + 0] = w_fc[kk * SEQ + t];
            lds_wfcp[(kk * SEQ + t) * 2 + 1] = w_fc[4 * SEQ + t];
        }
    }
    __syncthreads();

    // ---- per-lane weights: gate pair {ga,gb} = {2*j2, 2*j2+1} of unit k ----
    v2f wip[4], whp[4], bp;
    {
        const int ga = 2 * j2, gb = 2 * j2 + 1;
        const float sa = (ga == 2) ? 2.8853900817779268f : -1.4426950408889634f;
        const float sb = -1.4426950408889634f;  // gb is f (1) or o (3): always -log2e
        const int ra = ga * H + k, rb = gb * H + k;
        #pragma unroll
        for (int m = 0; m < 4; ++m) {
            float wa, wb;
            if (l == 0) {
                wa = (m < 2) ? w_ih0[ra * 2 + m] : 0.f;
                wb = (m < 2) ? w_ih0[rb * 2 + m] : 0.f;
            } else {
                wa = w_ih[((l - 1) * 16 + ra) * 4 + m];
                wb = w_ih[((l - 1) * 16 + rb) * 4 + m];
            }
            wip[m][0] = wa * sa; wip[m][1] = wb * sb;
            whp[m][0] = w_hh[(l * 16 + ra) * 4 + m] * sa;
            whp[m][1] = w_hh[(l * 16 + rb) * 4 + m] * sb;
        }
        bp[0] = (b_ih[l * 16 + ra] + b_hh[l * 16 + ra]) * sa;
        bp[1] = (b_ih[l * 16 + rb] + b_hh[l * 16 + rb]) * sb;
    }
    const float wl0 = w_lin[0], wl1 = w_lin[1], wl2 = w_lin[2], wl3 = w_lin[3];
    const float bl  = b_lin[0];
    const int wpbase = k * SEQ;

    // ---- state ----
    float c = 0.f;
    float q0 = 0.f, q1 = 0.f, q2 = 0.f, q3 = 0.f;  // h(tau-1), own layer, per-unit
    v2f acc2 = splat2(0.f);                         // {out[k]-acc, out[4]-acc}
    v2f pre;                                        // gate-pair pre-activation
    {
        const float2 xv0 = *(const float2*)&lds_x[0];
        const float xs0 = is_l0 ? xv0.x : 0.f;
        const float xs1 = is_l0 ? xv0.y : 0.f;
        pre = FMA2(wip[1], splat2(xs1), FMA2(wip[0], splat2(xs0), bp));
    }

    #define TICK_CORE(tau_, GATED, NXv, WVv)                                          \
    {                                                                                 \
        const float oq0 = q0, oq1 = q1, oq2 = q2, oq3 = q3;                           \
        /* ---- CHAIN: pair gates -> c -> h -> quad DPP ---- */                       \
        v2f G = FMA2(whp[3], splat2(oq3), FMA2(whp[2], splat2(oq2),                   \
                FMA2(whp[1], splat2(oq1), FMA2(whp[0], splat2(oq0), pre))));          \
        v2f E; E[0] = __builtin_amdgcn_exp2f(G[0]);                                   \
        E[1] = __builtin_amdgcn_exp2f(G[1]);                                          \
        v2f A = E + 1.f;      /* j2=0: {Ai,Af}; j2=1: {Dg,Ao} */                      \
        v2f X, Y;             /* X={Ai,Af}, Y={Dg,Ao} on ALL lanes */                 \
        X[0] = dppm<0x114, 0xF, 0xA, false>(A[0], A[0]);                              \
        X[1] = dppm<0x114, 0xF, 0xA, false>(A[1], A[1]);                              \
        Y[0] = dppm<0x104, 0xF, 0x5, false>(A[0], A[0]);                              \
        Y[1] = dppm<0x104, 0xF, 0x5, false>(A[1], A[1]);                              \
        const float M   = X[0] * Y[0];                                                \
        const float den = M * X[1];                                                   \
        const float num = fmaf(c, M, X[1] * (Y[0] - 2.f));                            \
        float cn = num * __builtin_amdgcn_rcpf(den);                                  \
        if (GATED) { const unsigned tt = (unsigned)((tau_) - 2 * l_raw);              \
                     cn = (tt < SEQ) ? cn : 0.f; }                                    \
        c = cn;                                                                       \
        const float Dc = 1.f + __builtin_amdgcn_exp2f(c * 2.8853900817779268f);       \
        const float hv = (Dc - 2.f) * __builtin_amdgcn_rcpf(Y[1] * Dc);               \
        q0 = dppm<0x00, 0xF, 0xF, true>(0.f, hv);                                     \
        q1 = dppm<0x55, 0xF, 0xF, true>(0.f, hv);                                     \
        q2 = dppm<0xAA, 0xF, 0xF, true>(0.f, hv);                                     \
        q3 = dppm<0xFF, 0xF, 0xF, true>(0.f, hv);                                     \
        /* ---- BURST: handoff p (layer l-1 -> l, lane-8), pre, head ---- */          \
        float p0 = dppm<0x118, 0xF, 0xF, true>(0.f, oq0);                             \
        p0 = dppm<0x142, 0x2, 0x3, false>(p0, oq0);                                   \
        p0 = dppm<0x143, 0x4, 0x3, false>(p0, oq0);                                   \
        float p1 = dppm<0x118, 0xF, 0xF, true>(0.f, oq1);                             \
        p1 = dppm<0x142, 0x2, 0x3, false>(p1, oq1);                                   \
        p1 = dppm<0x143, 0x4, 0x3, false>(p1, oq1);                                   \
        float p2 = dppm<0x118, 0xF, 0xF, true>(0.f, oq2);                             \
        p2 = dppm<0x142, 0x2, 0x3, false>(p2, oq2);                                   \
        p2 = dppm<0x143, 0x4, 0x3, false>(p2, oq2);                                   \
        float p3 = dppm<0x118, 0xF, 0xF, true>(0.f, oq3);                             \
        p3 = dppm<0x142, 0x2, 0x3, false>(p3, oq3);                                   \
        p3 = dppm<0x143, 0x4, 0x3, false>(p3, oq3);                                   \
        const float xs0 = is_l0 ? (NXv).x : p0;                                       \
        const float xs1 = is_l0 ? (NXv).y : p1;                                       \
        pre = FMA2(wip[3], splat2(p3), FMA2(wip[2], splat2(p2),                       \
              FMA2(wip[1], splat2(xs1), FMA2(wip[0], splat2(xs0), bp))));             \
        float tval = fmaf(oq0, wl0, fmaf(oq1, wl1, fmaf(oq2, wl2, fmaf(oq3, wl3, bl)))); \
        if (GATED) tval = ((unsigned)((tau_) - 9) < SEQ) ? tval : 0.f;                \
        v2f wvv; wvv[0] = (WVv).x; wvv[1] = (WVv).y;                                  \
        acc2 = FMA2(splat2(tval), wvv, acc2);                                         \
    }

    // ---- gated head: per-tick LDS loads, clamped indices ----
    for (int tau = 0; tau < HEAD; ++tau) {
        const float2 nx = *(const float2*)&lds_x[(tau + 1) * 2];
        int t4 = tau - 9; t4 = t4 < 0 ? 0 : t4;
        const float2 wv = *(const float2*)&lds_wfcp[(wpbase + t4) * 2];
        TICK_CORE(tau, true, nx, wv);
    }

    // ---- clean body: 75 chunks x 8 ticks; loads batched per chunk into regs.
    // Junk timesteps (t>609) on layers 0-3 cannot reach layer-4's consumed h
    // before the loop ends; wfc index tau-9 stays in [7,606]; x over-reads stay
    // inside the padded lds_x.
    for (int ch = 0; ch < 75; ++ch) {
        const int tau0 = HEAD + ch * 8;
        float2 xc_[8], wc_[8];
        #pragma unroll
        for (int i = 0; i < 8; ++i) {
            xc_[i] = *(const float2*)&lds_x[(tau0 + 1 + i) * 2];
            wc_[i] = *(const float2*)&lds_wfcp[(wpbase + tau0 + i - 9) * 2];
        }
        #pragma unroll
        for (int i = 0; i < 8; ++i) {
            TICK_CORE(tau0 + i, false, xc_[i], wc_[i]);
        }
    }

    // ---- gated tail (ticks 616..618) ----
    for (int tau = TAIL0; tau < NITER; ++tau) {
        const float2 nx = *(const float2*)&lds_x[(tau + 1) * 2];
        const float2 wv = *(const float2*)&lds_wfcp[(wpbase + tau - 9) * 2];
        TICK_CORE(tau, true, nx, wv);
    }
    #undef TICK_CORE

    // layer-4, j2=0 quad (lanes 32-35) writes the outputs
    if (lane >= 32 && lane < 36) {
        out[b * 5 + k] = acc2[0] + b_fc[k];
        if (k == 0) out[b * 5 + 4] = acc2[1] + b_fc[4];
    }
}

extern "C" void kernel_launch(void* const* d_in, const int* in_sizes, int n_in,
                              void* d_out, int out_size, void* d_ws, size_t ws_size,
                              hipStream_t stream)
{
    const float* x     = (const float*)d_in[0];
    const float* w_ih0 = (const float*)d_in[1];
    const float* w_ih  = (const float*)d_in[2];
    const float* w_hh  = (const float*)d_in[3];
    const float* b_ih  = (const float*)d_in[4];
    const float* b_hh  = (const float*)d_in[5];
    const float* w_lin = (const float*)d_in[6];
    const float* b_lin = (const float*)d_in[7];
    const float* w_fc  = (const float*)d_in[8];
    const float* b_fc  = (const float*)d_in[9];
    float* out = (float*)d_out;

    lstm_jk_kernel<<<dim3(BATCH), dim3(64), 0, stream>>>(
        x, w_ih0, w_ih, w_hh, b_ih, b_hh, w_lin, b_lin, w_fc, b_fc, out);
}